// Round 4
// baseline (199.500 us; speedup 1.0000x reference)
//
#include <hip/hip_runtime.h>

#define IMG_W 1024
#define IMG_H 1024
#define RPW   8     // rows per wave-strip

typedef float floatx4 __attribute__((ext_vector_type(4)));

__global__ __launch_bounds__(256) void dir_rhs_kernel(
    const float* __restrict__ u,
    const float* __restrict__ f,
    const float* __restrict__ wt,
    float* __restrict__ out)
{
    const int tid  = threadIdx.x;
    const int lane = tid & 63;
    const int wv   = tid >> 6;
    const int strip = (blockIdx.x << 2) + wv;    // 0..2047
    const int b   = strip >> 7;                  // 128 strips per image
    const int r0  = (strip & 127) * RPW;
    const int c0  = lane << 4;                   // 16 contiguous cols per lane
    const size_t img = (size_t)b << 20;

    const float* ub = u + img + c0;
    const float* fb = f + img + c0;
    float*       ob = out + img + c0;

    const float w00 = wt[0], w01 = wt[1], w02 = wt[2];
    const float w10 = wt[3], w11 = wt[4], w12 = wt[5];
    const float w20 = wt[6], w21 = wt[7], w22 = wt[8];
    const float cof = (float)(-(1.0 / 1023.0) * (1.0 / 1023.0) / 4.0);

    // raw load of a v-row (zeros outside interior rows); no shfl here so the
    // prefetch never forces an early waitcnt
    auto load_v = [&](int g, float* a) {
        if (g >= 1 && g <= IMG_H - 2) {
            const floatx4* p = (const floatx4*)(ub + (size_t)g * IMG_W);
            floatx4 q0 = p[0], q1 = p[1], q2 = p[2], q3 = p[3];
            a[0]=q0.x; a[1]=q0.y; a[2]=q0.z; a[3]=q0.w;
            a[4]=q1.x; a[5]=q1.y; a[6]=q1.z; a[7]=q1.w;
            a[8]=q2.x; a[9]=q2.y; a[10]=q2.z; a[11]=q2.w;
            a[12]=q3.x; a[13]=q3.y; a[14]=q3.z; a[15]=q3.w;
        } else {
            #pragma unroll
            for (int e = 0; e < 16; e++) a[e] = 0.f;
        }
    };
    auto load_f = [&](int g, float* a) {
        const floatx4* p = (const floatx4*)(fb + (size_t)g * IMG_W);
        floatx4 q0 = p[0], q1 = p[1], q2 = p[2], q3 = p[3];
        a[0]=q0.x; a[1]=q0.y; a[2]=q0.z; a[3]=q0.w;
        a[4]=q1.x; a[5]=q1.y; a[6]=q1.z; a[7]=q1.w;
        a[8]=q2.x; a[9]=q2.y; a[10]=q2.z; a[11]=q2.w;
        a[12]=q3.x; a[13]=q3.y; a[14]=q3.z; a[15]=q3.w;
    };
    // boundary-column zeroing + halo exchange (consumes the loads)
    auto finalize = [&](float* a, float& lh, float& rh) {
        if (lane == 0)  a[0]  = 0.f;   // col 0 is boundary in v
        if (lane == 63) a[15] = 0.f;   // col 1023 is boundary in v
        lh = __shfl_up(a[15], 1, 64);  // col c0-1 from left lane
        rh = __shfl_down(a[0], 1, 64); // col c0+16 from right lane
    };

    float vm[16], vc[16], vp[16], vn[16], fr[16], fn[16];
    float lhm, rhm, lhc, rhc, lhp, rhp;

    load_v(r0 - 1, vm);
    load_v(r0,     vc);
    load_v(r0 + 1, vp);
    load_f(r0,     fr);
    finalize(vm, lhm, rhm);
    finalize(vc, lhc, rhc);

    #pragma unroll
    for (int k = 0; k < RPW; k++) {
        if (k < RPW - 1) {              // prefetch two rows ahead
            load_v(r0 + k + 2, vn);
            load_f(r0 + k + 1, fn);
        }
        finalize(vp, lhp, rhp);         // waits only on vp's 4 loads

        const int g = r0 + k;
        float res[16];
        #pragma unroll
        for (int e = 0; e < 16; e++) {
            const float lm = (e == 0) ? lhm : vm[e - 1];
            const float rm = (e == 15) ? rhm : vm[e + 1];
            const float lc = (e == 0) ? lhc : vc[e - 1];
            const float rc = (e == 15) ? rhc : vc[e + 1];
            const float lp = (e == 0) ? lhp : vp[e - 1];
            const float rp = (e == 15) ? rhp : vp[e + 1];
            float acc = cof * fr[e];
            acc += w00 * lm + w01 * vm[e] + w02 * rm;
            acc += w10 * lc + w11 * vc[e] + w12 * rc;
            acc += w20 * lp + w21 * vp[e] + w22 * rp;
            res[e] = acc;
        }
        if (g == 0 || g == IMG_H - 1) {
            #pragma unroll
            for (int e = 0; e < 16; e++) res[e] = 0.f;   // boundary rows
        }
        if (lane == 0)  res[0]  = 0.f;  // boundary cols
        if (lane == 63) res[15] = 0.f;

        floatx4* o4 = (floatx4*)(ob + (size_t)g * IMG_W);
        floatx4 s0 = { res[0],  res[1],  res[2],  res[3]  };
        floatx4 s1 = { res[4],  res[5],  res[6],  res[7]  };
        floatx4 s2 = { res[8],  res[9],  res[10], res[11] };
        floatx4 s3 = { res[12], res[13], res[14], res[15] };
        __builtin_nontemporal_store(s0, o4 + 0);
        __builtin_nontemporal_store(s1, o4 + 1);
        __builtin_nontemporal_store(s2, o4 + 2);
        __builtin_nontemporal_store(s3, o4 + 3);

        if (k < RPW - 1) {              // rotate rolling window
            #pragma unroll
            for (int e = 0; e < 16; e++) { vm[e] = vc[e]; vc[e] = vp[e]; vp[e] = vn[e]; fr[e] = fn[e]; }
            lhm = lhc; rhm = rhc; lhc = lhp; rhc = rhp;
        }
    }
}

extern "C" void kernel_launch(void* const* d_in, const int* in_sizes, int n_in,
                              void* d_out, int out_size, void* d_ws, size_t ws_size,
                              hipStream_t stream) {
    const float* u  = (const float*)d_in[0];
    const float* f  = (const float*)d_in[1];
    const float* wt = (const float*)d_in[2];
    float* out = (float*)d_out;

    const int B = 16;
    // 2048 wave-strips (16 images x 128 strips), 4 waves per 256-thread block
    dim3 grid(B * (IMG_H / RPW) / 4);
    dim3 block(256);
    dir_rhs_kernel<<<grid, block, 0, stream>>>(u, f, wt, out);
}

// Round 5
// 178.825 us; speedup vs baseline: 1.1156x; 1.1156x over previous
//
#include <hip/hip_runtime.h>

#define IMG_W 1024
#define IMG_H 1024

__global__ __launch_bounds__(256) void dir_rhs_kernel(
    const float* __restrict__ u,
    const float* __restrict__ f,
    const float* __restrict__ wt,
    float* __restrict__ out)
{
    // XCD-aware swizzle: blocks dispatch round-robin over 8 XCDs, so give
    // XCD x the contiguous row range [x*2048, (x+1)*2048). Neighbor rows
    // (i-1, i, i+1) then live on the SAME XCD and share its L2, cutting
    // L3->L2 fabric fills of u from 3x to ~1x.
    const int phys = blockIdx.x;          // 0..16383
    const int xcd  = phys & 7;
    const int seq  = phys >> 3;           // 0..2047, consecutive on one XCD
    const int gr   = (xcd << 11) + seq;   // global row id: b*1024 + i
    const int b    = gr >> 10;
    const int i    = gr & (IMG_H - 1);

    const int tid = threadIdx.x;           // 0..255
    const int j0  = tid << 2;              // 4 columns per thread
    const size_t img = (size_t)b << 20;    // 1024*1024 elems per image

    float4* out4 = (float4*)(out + img + (size_t)i * IMG_W + j0);

    // Boundary rows: pure Dirichlet value (0)
    if (i == 0 || i == IMG_H - 1) {
        *out4 = make_float4(0.f, 0.f, 0.f, 0.f);
        return;
    }

    // Weights (broadcast loads, L1-cached)
    const float w00 = wt[0], w01 = wt[1], w02 = wt[2];
    const float w10 = wt[3], w11 = wt[4], w12 = wt[5];
    const float w20 = wt[6], w21 = wt[7], w22 = wt[8];
    const float cof = (float)(-(1.0 / 1023.0) * (1.0 / 1023.0) / 4.0);

    const float* urow = u + img + (size_t)i * IMG_W;

    float vm[6], vc[6], vp[6];

    const bool left_edge  = (j0 == 0);
    const bool right_edge = (j0 + 4 >= IMG_W);   // thread covering col 1023

    // ---- center row i (always interior here: 1 <= i <= 1022) ----
    {
        float4 c = *(const float4*)(urow + j0);
        vc[1] = c.x; vc[2] = c.y; vc[3] = c.z; vc[4] = c.w;
        vc[0] = left_edge  ? 0.f : urow[j0 - 1];
        vc[5] = right_edge ? 0.f : urow[j0 + 4];
        if (left_edge)  vc[1] = 0.f;   // col 0 is boundary in v
        if (right_edge) vc[4] = 0.f;   // col 1023 is boundary in v
    }
    // ---- north row i-1 ----
    if (i == 1) {
        #pragma unroll
        for (int k = 0; k < 6; k++) vm[k] = 0.f;   // row 0 is boundary in v
    } else {
        const float* r = urow - IMG_W;
        float4 c = *(const float4*)(r + j0);
        vm[1] = c.x; vm[2] = c.y; vm[3] = c.z; vm[4] = c.w;
        vm[0] = left_edge  ? 0.f : r[j0 - 1];
        vm[5] = right_edge ? 0.f : r[j0 + 4];
        if (left_edge)  vm[1] = 0.f;
        if (right_edge) vm[4] = 0.f;
    }
    // ---- south row i+1 ----
    if (i == IMG_H - 2) {
        #pragma unroll
        for (int k = 0; k < 6; k++) vp[k] = 0.f;   // row 1023 is boundary in v
    } else {
        const float* r = urow + IMG_W;
        float4 c = *(const float4*)(r + j0);
        vp[1] = c.x; vp[2] = c.y; vp[3] = c.z; vp[4] = c.w;
        vp[0] = left_edge  ? 0.f : r[j0 - 1];
        vp[5] = right_edge ? 0.f : r[j0 + 4];
        if (left_edge)  vp[1] = 0.f;
        if (right_edge) vp[4] = 0.f;
    }

    // ---- source term ----
    float4 f4 = *(const float4*)(f + img + (size_t)i * IMG_W + j0);
    float ff[4] = {f4.x, f4.y, f4.z, f4.w};

    float res[4];
    #pragma unroll
    for (int e = 0; e < 4; e++) {
        float acc = cof * ff[e];
        acc += w00 * vm[e] + w01 * vm[e + 1] + w02 * vm[e + 2];
        acc += w10 * vc[e] + w11 * vc[e + 1] + w12 * vc[e + 2];
        acc += w20 * vp[e] + w21 * vp[e + 1] + w22 * vp[e + 2];
        res[e] = acc;
    }
    // Boundary columns stay at the Dirichlet value
    if (left_edge)  res[0] = 0.f;
    if (right_edge) res[3] = 0.f;

    *out4 = make_float4(res[0], res[1], res[2], res[3]);
}

extern "C" void kernel_launch(void* const* d_in, const int* in_sizes, int n_in,
                              void* d_out, int out_size, void* d_ws, size_t ws_size,
                              hipStream_t stream) {
    const float* u  = (const float*)d_in[0];
    const float* f  = (const float*)d_in[1];
    const float* wt = (const float*)d_in[2];
    float* out = (float*)d_out;

    const int B = 16;
    dim3 grid(B * IMG_H);   // one block per (batch, row), XCD-swizzled inside
    dim3 block(256);        // 256 threads * 4 cols = 1024-wide row
    dir_rhs_kernel<<<grid, block, 0, stream>>>(u, f, wt, out);
}